// Round 15
// baseline (342.812 us; speedup 1.0000x reference)
//
#include <hip/hip_runtime.h>
#include <hip/hip_bf16.h>

typedef __bf16 bf16;
typedef __bf16 bf16x2 __attribute__((ext_vector_type(2)));
typedef __bf16 bf16x4 __attribute__((ext_vector_type(4)));
typedef __bf16 bf16x8 __attribute__((ext_vector_type(8)));
typedef float f32x4 __attribute__((ext_vector_type(4)));
typedef float f32x16 __attribute__((ext_vector_type(16)));
typedef unsigned u32x2 __attribute__((ext_vector_type(2)));

#define DIM 1536
#define NH 12
#define HD 128
#define SEQ 1560
#define KV 9360
#define KVP 9408      // padded to 294*32 so staging never needs clamps
#define SINK 1560
#define NEWBASE 7800  // k_cat rows [7800,9360) are the new tokens
// logits computed in log2 domain: Q pre-scaled by HD^-0.5 * log2(e)
#define QSCALE_L2E (0.08838834764831845f * 1.4426950408889634f)
#define NSPLIT 6
#define CHUNK 1568    // 49 tiles of 32; 6*1568 = 9408 = KVP exactly
#define NT 49
#define KB 32         // keys per tile
#define QBLK 256      // 4 waves x 64 q-rows (2 qsets of 32)
#define NQT 7         // ceil(1560/256)

__device__ __forceinline__ void gl_lds16(const void* g, void* l) {
  __builtin_amdgcn_global_load_lds(
      (const __attribute__((address_space(1))) unsigned int*)g,
      (__attribute__((address_space(3))) unsigned int*)l, 16, 0, 0);
}

__device__ __forceinline__ f32x16 mfma32(bf16x8 a, bf16x8 b, f32x16 c) {
  return __builtin_amdgcn_mfma_f32_32x32x16_bf16(a, b, c, 0, 0, 0);
}

// ---------------- fused cast f32 -> bf16 (x + 4 weights) ----------------
struct CastBatch {
  const float* src[5];
  bf16* dst[5];
  int n[5];
};
__global__ __launch_bounds__(256) void castall(CastBatch cb) {
  const float* src = cb.src[blockIdx.y];
  bf16* dst = cb.dst[blockIdx.y];
  int n = cb.n[blockIdx.y];
  int i = (blockIdx.x * 256 + threadIdx.x) * 8;
  if (i < n) {
    float4 a = *(const float4*)(src + i);
    float4 b = *(const float4*)(src + i + 4);
    bf16x8 o;
    o[0] = (bf16)a.x; o[1] = (bf16)a.y; o[2] = (bf16)a.z; o[3] = (bf16)a.w;
    o[4] = (bf16)b.x; o[5] = (bf16)b.y; o[6] = (bf16)b.z; o[7] = (bf16)b.w;
    *(bf16x8*)(dst + i) = o;
  }
}

// ---- zero the KVP padding rows/cols so no ws read is ever uninitialized ----
__global__ __launch_bounds__(256) void clear_pad(bf16* __restrict__ Kcat,
                                                 bf16* __restrict__ Vt) {
  int h = blockIdx.y;
  int i = blockIdx.x * 256 + threadIdx.x;  // [0, 6144)
  if (i < (KVP - KV) * HD) {
    int r = KV + i / HD, d = i % HD;
    Kcat[((size_t)h * KVP + r) * HD + d] = (bf16)0.f;
    int dv = i / (KVP - KV), j = KV + i % (KVP - KV);
    Vt[((size_t)h * HD + dv) * KVP + j] = (bf16)0.f;
  }
}

// ---------------- GEMM: C[M,N] = A[M,K] * B[N,K]^T + bias, f32 out ----------------
struct GemmBatch {
  const bf16* B[3];
  const float* bias[3];
  float* C[3];
};

#define BM 128
#define BN 128
#define BK 32

__global__ __launch_bounds__(256, 2) void gemm_bt(const bf16* __restrict__ A,
                                                  GemmBatch gb, int M) {
  const bf16* Bw = gb.B[blockIdx.z];
  const float* bias = gb.bias[blockIdx.z];
  float* C = gb.C[blockIdx.z];
  int bm = blockIdx.x * BM;
  int bn = blockIdx.y * BN;

  __shared__ bf16 Alds[2][BM][BK];
  __shared__ bf16 Blds[2][BN][BK];

  int t = threadIdx.x;
  int lane = t & 63;
  int wave = t >> 6;
  int wr = wave >> 1, wc = wave & 1;
  int fr = lane & 15;
  int fo = (lane >> 4) * 8;

  f32x4 acc[4][4] = {};

  const int NK = DIM / BK;  // 48
  int colA = (lane & 3) * 8;
  int lrow = lane >> 2;

#define STAGEG(buf, k0)                                                     \
  {                                                                         \
    _Pragma("unroll") for (int p = 0; p < 2; ++p) {                         \
      int rbase = wave * 16 + p * 64;                                       \
      int ga = bm + rbase + lrow;                                           \
      if (ga > M - 1) ga = M - 1;                                           \
      gl_lds16(A + (size_t)ga * DIM + (k0) + colA, &Alds[buf][rbase][0]);   \
      int gbv = bn + rbase + lrow;                                          \
      gl_lds16(Bw + (size_t)gbv * DIM + (k0) + colA, &Blds[buf][rbase][0]); \
    }                                                                       \
  }

  STAGEG(0, 0);
  int cur = 0;
  for (int ks = 0; ks < NK; ++ks) {
    __syncthreads();  // drains vmcnt -> buf[cur] ready
    if (ks + 1 < NK) STAGEG(cur ^ 1, (ks + 1) * BK);
    bf16x8 af[4], bfv[4];
#pragma unroll
    for (int i = 0; i < 4; ++i)
      af[i] = *(const bf16x8*)&Alds[cur][wr * 64 + i * 16 + fr][fo];
#pragma unroll
    for (int j = 0; j < 4; ++j)
      bfv[j] = *(const bf16x8*)&Blds[cur][wc * 64 + j * 16 + fr][fo];
#pragma unroll
    for (int i = 0; i < 4; ++i)
#pragma unroll
      for (int j = 0; j < 4; ++j)
        acc[i][j] = __builtin_amdgcn_mfma_f32_16x16x32_bf16(af[i], bfv[j],
                                                            acc[i][j], 0, 0, 0);
    cur ^= 1;
  }
#undef STAGEG

  int g4 = (lane >> 4) * 4;
#pragma unroll
  for (int i = 0; i < 4; ++i) {
    int mbase = bm + wr * 64 + i * 16 + g4;
#pragma unroll
    for (int j = 0; j < 4; ++j) {
      int col = bn + wc * 64 + j * 16 + fr;
      float bv = bias[col];
#pragma unroll
      for (int r = 0; r < 4; ++r) {
        int m = mbase + r;
        if (m < M) C[(size_t)m * DIM + col] = acc[i][j][r] + bv;
      }
    }
  }
}

// ---------------- RMSNorm + RoPE for q,k ----------------
__global__ __launch_bounds__(256) void norm_rope(
    const float* __restrict__ qraw, const float* __restrict__ kraw,
    const float* __restrict__ nqw, const float* __restrict__ nkw,
    const float* __restrict__ fcos, const float* __restrict__ fsin,
    bf16* __restrict__ Qh, bf16* __restrict__ Kcat) {
  int tok = blockIdx.x;
  int tid = threadIdx.x;
  const float* qr = qraw + (size_t)tok * DIM;
  const float* kr = kraw + (size_t)tok * DIM;
  float sq = 0.f, sk = 0.f;
  for (int c = tid; c < DIM; c += 256) {
    float a = qr[c];
    sq += a * a;
    float b = kr[c];
    sk += b * b;
  }
#pragma unroll
  for (int off = 32; off; off >>= 1) {
    sq += __shfl_down(sq, off);
    sk += __shfl_down(sk, off);
  }
  __shared__ float red[2][4];
  int w = tid >> 6;
  if ((tid & 63) == 0) {
    red[0][w] = sq;
    red[1][w] = sk;
  }
  __syncthreads();
  sq = red[0][0] + red[0][1] + red[0][2] + red[0][3];
  sk = red[1][0] + red[1][1] + red[1][2] + red[1][3];
  float rsq = rsqrtf(sq * (1.0f / DIM) + 1e-6f);
  float rsk = rsqrtf(sk * (1.0f / DIM) + 1e-6f);

  int hrow = tok / 52, wrow = tok % 52;
  for (int p = tid; p < NH * 64; p += 256) {
    int n = p >> 6, i = p & 63;
    int trow = (i < 22) ? 6 : (i < 43 ? hrow : wrow);
    float cs = fcos[trow * 64 + i];
    float sn = fsin[trow * 64 + i];
    int c = n * HD + 2 * i;
    float xr = qr[c] * rsq * nqw[c];
    float xi = qr[c + 1] * rsq * nqw[c + 1];
    bf16x2 qo;
    qo[0] = (bf16)((xr * cs - xi * sn) * QSCALE_L2E);
    qo[1] = (bf16)((xr * sn + xi * cs) * QSCALE_L2E);
    *(bf16x2*)(Qh + ((size_t)n * SEQ + tok) * HD + 2 * i) = qo;
    float yr = kr[c] * rsk * nkw[c];
    float yi = kr[c + 1] * rsk * nkw[c + 1];
    bf16x2 ko;
    ko[0] = (bf16)(yr * cs - yi * sn);
    ko[1] = (bf16)(yr * sn + yi * cs);
    *(bf16x2*)(Kcat + ((size_t)n * KVP + NEWBASE + tok) * HD + 2 * i) = ko;
  }
}

// ---------------- gather cache_k rows into K_cat ----------------
__global__ __launch_bounds__(256) void build_kcat(const float* __restrict__ cache_k,
                                                  bf16* __restrict__ Kcat) {
  int j = blockIdx.x;  // 0..7799
  int src = j < SINK ? j : j + SINK;
  const float* sp = cache_k + (size_t)src * DIM;
  for (int c4 = threadIdx.x; c4 < DIM / 4; c4 += 256) {
    float4 v = *(const float4*)(sp + c4 * 4);
    int c = c4 * 4;
    int n = c >> 7, d = c & 127;
    bf16x4 o;
    o[0] = (bf16)v.x; o[1] = (bf16)v.y; o[2] = (bf16)v.z; o[3] = (bf16)v.w;
    *(bf16x4*)(Kcat + ((size_t)n * KVP + j) * HD + d) = o;
  }
}

// ---------------- build transposed V: Vt[h][d][j] ----------------
__global__ __launch_bounds__(256) void build_vt(const float* __restrict__ cache_v,
                                                const float* __restrict__ vraw,
                                                bf16* __restrict__ Vt) {
  int h = blockIdx.y;
  int j0 = blockIdx.x * 64;
  __shared__ bf16 T[128][72];
  int tid = threadIdx.x;
  for (int idx = tid; idx < 64 * 32; idx += 256) {
    int jl = idx >> 5, s = idx & 31;
    int j = j0 + jl;
    if (j >= KV) continue;
    const float* sp;
    if (j < NEWBASE) {
      int srcj = j < SINK ? j : j + SINK;
      sp = cache_v + (size_t)srcj * DIM + h * HD;
    } else {
      sp = vraw + (size_t)(j - NEWBASE) * DIM + h * HD;
    }
    float4 v = *(const float4*)(sp + s * 4);
    T[s * 4 + 0][jl] = (bf16)v.x;
    T[s * 4 + 1][jl] = (bf16)v.y;
    T[s * 4 + 2][jl] = (bf16)v.z;
    T[s * 4 + 3][jl] = (bf16)v.w;
  }
  __syncthreads();
  for (int idx = tid; idx < 128 * 16; idx += 256) {
    int d = idx >> 4, g = idx & 15;
    int j = j0 + g * 4;
    if (j + 4 > KV) continue;
    bf16x4 o;
    o[0] = T[d][4 * g];
    o[1] = T[d][4 * g + 1];
    o[2] = T[d][4 * g + 2];
    o[3] = T[d][4 * g + 3];
    *(bf16x4*)(Vt + ((size_t)h * HD + d) * KVP + j) = o;
  }
}

// ---- flash attention: KB=32, DUAL q-set per wave (64 q/wave), dbuf staging ----
__global__ __launch_bounds__(256, 2) void attn_split(const bf16* __restrict__ Qh,
                                                     const bf16* __restrict__ Kcat,
                                                     const bf16* __restrict__ Vtg,
                                                     float* __restrict__ Opart,
                                                     float* __restrict__ MLpart) {
  // XCD swizzle: 504 = 8*63 exactly
  int orig = blockIdx.x;
  int wgid = (orig & 7) * 63 + (orig >> 3);
  int qt = wgid % NQT;
  int rest = wgid / NQT;
  int h = rest % NH;
  int sp = rest / NH;
  int q0 = qt * QBLK;
  int c0 = sp * CHUNK;

  int t = threadIdx.x, lane = t & 63, w = t >> 6;
  int ql = lane & 31, hi = lane >> 5;

  __shared__ __align__(16) bf16 Klds[2][KB * 128];   // 2 x 8 KB, 4-bit XOR swizzle
  __shared__ __align__(16) bf16 Vlds[2][128 * KB];   // 2 x 8 KB, 2-bit XOR swizzle

  // Q fragments for TWO qsets: q = q0 + w*64 + s*32 + ql
  bf16x8 qreg0[8], qreg1[8];
  {
    int qr0 = q0 + w * 64 + ql;
    int qc0 = qr0 < SEQ ? qr0 : SEQ - 1;
    const bf16* Qp0 = Qh + ((size_t)h * SEQ + qc0) * HD + hi * 8;
#pragma unroll
    for (int ks = 0; ks < 8; ++ks) qreg0[ks] = *(const bf16x8*)(Qp0 + ks * 16);
    int qr1 = q0 + w * 64 + 32 + ql;
    int qc1 = qr1 < SEQ ? qr1 : SEQ - 1;
    const bf16* Qp1 = Qh + ((size_t)h * SEQ + qc1) * HD + hi * 8;
#pragma unroll
    for (int ks = 0; ks < 8; ++ks) qreg1[ks] = *(const bf16x8*)(Qp1 + ks * 16);
  }

  // staging: linear LDS dest (gl_lds), pre-swizzled global source
  int kadd[2], vadd[2];
#pragma unroll
  for (int p = 0; p < 2; ++p) {
    int m = (2 * w + p) * 64 + lane;  // 16B-chunk index, 0..511
    int rK = m >> 4, cK = m & 15;     // K row 0..31, 16 chunks/row
    kadd[p] = rK * HD + (cK ^ (rK & 15)) * 8;
    int dV = m >> 2, cV = m & 3;      // V row(d) 0..127, 4 chunks/row
    vadd[p] = dV * KVP + (cV ^ ((dV >> 1) & 3)) * 8;
  }

  // swizzled LDS read offsets
  int koff[8];
#pragma unroll
  for (int ks = 0; ks < 8; ++ks)
    koff[ks] = ql * 256 + (((ks * 2 + hi) ^ (ql & 15)) * 16);
  int voff[4][2];
#pragma unroll
  for (int db = 0; db < 4; ++db)
#pragma unroll
    for (int ks = 0; ks < 2; ++ks)
      voff[db][ks] = (db * 32 + ql) * 64 + (((ks * 2 + hi) ^ ((ql >> 1) & 3)) * 16);

  const bf16* Khp = Kcat + (size_t)h * KVP * HD;
  const bf16* Vhp = Vtg + (size_t)h * HD * KVP;

  f32x16 oacc0[4] = {}, oacc1[4] = {};
  float m_q0 = -1e38f, l_q0 = 0.f;
  float m_q1 = -1e38f, l_q1 = 0.f;

#define STAGE(buf, j0)                                                        \
  {                                                                           \
    const bf16* Ks = Khp + (size_t)(j0)*HD;                                   \
    const bf16* Vs = Vhp + (j0);                                              \
    _Pragma("unroll") for (int p = 0; p < 2; ++p) {                           \
      gl_lds16(Ks + kadd[p], (char*)&Klds[buf][0] + w * 2048 + p * 1024);     \
      gl_lds16(Vs + vadd[p], (char*)&Vlds[buf][0] + w * 2048 + p * 1024);     \
    }                                                                         \
  }

  // pack one qset's probabilities into an A-fragment (cvt_pk + permlane swap)
#define PACK(SRC, PA)                                                         \
  _Pragma("unroll") for (int ks = 0; ks < 2; ++ks) {                          \
    const int r0 = ks * 8;                                                    \
    bf16x2 p0, p1, p2, p3;                                                    \
    p0[0] = (bf16)SRC[r0 + 0]; p0[1] = (bf16)SRC[r0 + 1];                     \
    p1[0] = (bf16)SRC[r0 + 2]; p1[1] = (bf16)SRC[r0 + 3];                     \
    p2[0] = (bf16)SRC[r0 + 4]; p2[1] = (bf16)SRC[r0 + 5];                     \
    p3[0] = (bf16)SRC[r0 + 6]; p3[1] = (bf16)SRC[r0 + 7];                     \
    unsigned x0 = __builtin_bit_cast(unsigned, p0);                           \
    unsigned x1 = __builtin_bit_cast(unsigned, p1);                           \
    unsigned y0 = __builtin_bit_cast(unsigned, p2);                           \
    unsigned y1 = __builtin_bit_cast(unsigned, p3);                           \
    u32x2 r0v = __builtin_amdgcn_permlane32_swap(x0, y0, false, false);       \
    u32x2 r1v = __builtin_amdgcn_permlane32_swap(x1, y1, false, false);       \
    int4 tmp;                                                                 \
    tmp.x = (int)r0v[0];                                                      \
    tmp.y = (int)r1v[0];                                                      \
    tmp.z = (int)r0v[1];                                                      \
    tmp.w = (int)r1v[1];                                                      \
    PA[ks] = __builtin_bit_cast(bf16x8, tmp);                                 \
  }

  STAGE(0, c0);
  __syncthreads();  // drain -> buf0 ready
  int cur = 0;

#pragma unroll 1
  for (int ti = 0; ti < NT; ++ti) {
    int j0 = c0 + ti * KB;
    if (ti + 1 < NT) STAGE(cur ^ 1, j0 + KB);  // prefetch overlaps compute

    const char* Kc = (const char*)&Klds[cur][0];
    const char* Vc = (const char*)&Vlds[cur][0];

    // S^T = K·Q^T for both qsets; each K-fragment read feeds 2 MFMAs
    f32x16 s0 = {}, s1 = {};
    __builtin_amdgcn_s_setprio(1);
#pragma unroll
    for (int ks = 0; ks < 8; ++ks) {
      bf16x8 kf = *(const bf16x8*)(Kc + koff[ks]);
      s0 = mfma32(kf, qreg0[ks], s0);
      s1 = mfma32(kf, qreg1[ks], s1);
    }
    __builtin_amdgcn_s_setprio(0);

    if (j0 + KB > KV) {
#pragma unroll
      for (int reg = 0; reg < 16; ++reg) {
        int kk = (reg & 3) + 8 * (reg >> 2) + 4 * hi;
        if (j0 + kk >= KV) {
          s0[reg] = -1e38f;
          s1[reg] = -1e38f;
        }
      }
    }

    // tree max per qset + partner merge
    float mx0, mx1;
    {
      float m8[8];
#pragma unroll
      for (int r = 0; r < 8; ++r) m8[r] = fmaxf(s0[r], s0[r + 8]);
      float mx = fmaxf(fmaxf(fmaxf(m8[0], m8[4]), fmaxf(m8[1], m8[5])),
                       fmaxf(fmaxf(m8[2], m8[6]), fmaxf(m8[3], m8[7])));
      mx0 = fmaxf(mx, __shfl_xor(mx, 32));
#pragma unroll
      for (int r = 0; r < 8; ++r) m8[r] = fmaxf(s1[r], s1[r + 8]);
      mx = fmaxf(fmaxf(fmaxf(m8[0], m8[4]), fmaxf(m8[1], m8[5])),
                 fmaxf(fmaxf(m8[2], m8[6]), fmaxf(m8[3], m8[7])));
      mx1 = fmaxf(mx, __shfl_xor(mx, 32));
    }

    // defer-max: rescale only when either qset's max grows by > 8 (log2 units)
    if (__any(fmaxf(mx0 - m_q0, mx1 - m_q1) > 8.f)) {
      float mn0 = fmaxf(m_q0, mx0);
      float c0r = exp2f(m_q0 - mn0);
      m_q0 = mn0;
      l_q0 *= c0r;
      float mn1 = fmaxf(m_q1, mx1);
      float c1r = exp2f(m_q1 - mn1);
      m_q1 = mn1;
      l_q1 *= c1r;
#pragma unroll
      for (int reg = 0; reg < 16; ++reg) {
        int qsrc = (reg & 3) + 8 * (reg >> 2) + 4 * hi;
        float ca = __shfl(c0r, qsrc);
        float cb = __shfl(c1r, qsrc);
#pragma unroll
        for (int db = 0; db < 4; ++db) {
          oacc0[db][reg] *= ca;
          oacc1[db][reg] *= cb;
        }
      }
    }

    // P = exp2(s - m), tree sum, pack per qset
    bf16x8 pa0[2], pa1[2];
    {
#pragma unroll
      for (int r = 0; r < 16; ++r) s0[r] = exp2f(s0[r] - m_q0);
      float t8[8];
#pragma unroll
      for (int r = 0; r < 8; ++r) t8[r] = s0[r] + s0[r + 8];
      float sum = ((t8[0] + t8[4]) + (t8[1] + t8[5])) +
                  ((t8[2] + t8[6]) + (t8[3] + t8[7]));
      sum += __shfl_xor(sum, 32);
      l_q0 += sum;
      PACK(s0, pa0);
#pragma unroll
      for (int r = 0; r < 16; ++r) s1[r] = exp2f(s1[r] - m_q1);
#pragma unroll
      for (int r = 0; r < 8; ++r) t8[r] = s1[r] + s1[r + 8];
      sum = ((t8[0] + t8[4]) + (t8[1] + t8[5])) +
            ((t8[2] + t8[6]) + (t8[3] + t8[7]));
      sum += __shfl_xor(sum, 32);
      l_q1 += sum;
      PACK(s1, pa1);
    }

    // O += P·V for both qsets; each V-fragment read feeds 2 MFMAs
    __builtin_amdgcn_s_setprio(1);
#pragma unroll
    for (int db = 0; db < 4; ++db)
#pragma unroll
      for (int ks = 0; ks < 2; ++ks) {
        bf16x8 vf = *(const bf16x8*)(Vc + voff[db][ks]);
        oacc0[db] = mfma32(pa0[ks], vf, oacc0[db]);
        oacc1[db] = mfma32(pa1[ks], vf, oacc1[db]);
      }
    __builtin_amdgcn_s_setprio(0);

    __syncthreads();  // drains next-tile loads + WAR on cur
    cur ^= 1;
  }
#undef PACK
#undef STAGE

  // store unnormalized partials for both qsets
  float* Oh = Opart + ((size_t)sp * NH + h) * SEQ * HD;
  float* MLh = MLpart + ((size_t)sp * NH + h) * SEQ * 2;
#pragma unroll
  for (int reg = 0; reg < 16; ++reg) {
    int qb = q0 + w * 64 + (reg & 3) + 8 * (reg >> 2) + 4 * hi;
    if (qb < SEQ) {
#pragma unroll
      for (int db = 0; db < 4; ++db)
        Oh[(size_t)qb * HD + db * 32 + ql] = oacc0[db][reg];
    }
    int qb1 = qb + 32;
    if (qb1 < SEQ) {
#pragma unroll
      for (int db = 0; db < 4; ++db)
        Oh[(size_t)qb1 * HD + db * 32 + ql] = oacc1[db][reg];
    }
  }
  if (lane < 32) {
    int q = q0 + w * 64 + ql;
    if (q < SEQ) {
      MLh[q * 2 + 0] = m_q0;
      MLh[q * 2 + 1] = l_q0;
    }
    if (q + 32 < SEQ) {
      MLh[(q + 32) * 2 + 0] = m_q1;
      MLh[(q + 32) * 2 + 1] = l_q1;
    }
  }
}

// ---------------- merge split partials (log2-domain m) ----------------
__global__ __launch_bounds__(256) void attn_merge(const float* __restrict__ Opart,
                                                  const float* __restrict__ MLpart,
                                                  bf16* __restrict__ Aout) {
  int idx = blockIdx.x * 2 + (threadIdx.x >> 7);
  if (idx >= NH * SEQ) return;
  int d = threadIdx.x & 127;
  int h = idx / SEQ, q = idx % SEQ;
  float m[NSPLIT];
  float M = -1e38f;
#pragma unroll
  for (int s = 0; s < NSPLIT; ++s) {
    m[s] = MLpart[(((size_t)s * NH + h) * SEQ + q) * 2];
    M = fmaxf(M, m[s]);
  }
  float L = 0.f, o = 0.f;
#pragma unroll
  for (int s = 0; s < NSPLIT; ++s) {
    float wgt = exp2f(m[s] - M);
    L += MLpart[(((size_t)s * NH + h) * SEQ + q) * 2 + 1] * wgt;
    o += Opart[((((size_t)s * NH + h) * SEQ + q)) * HD + d] * wgt;
  }
  Aout[(size_t)q * DIM + h * HD + d] = (bf16)(o / L);
}

// ---------------- host ----------------
extern "C" void kernel_launch(void* const* d_in, const int* in_sizes, int n_in,
                              void* d_out, int out_size, void* d_ws, size_t ws_size,
                              hipStream_t stream) {
  const float* x = (const float*)d_in[0];
  const float* Wq = (const float*)d_in[1];
  const float* bq = (const float*)d_in[2];
  const float* Wk = (const float*)d_in[3];
  const float* bk = (const float*)d_in[4];
  const float* Wv = (const float*)d_in[5];
  const float* bv = (const float*)d_in[6];
  const float* Wo = (const float*)d_in[7];
  const float* bo = (const float*)d_in[8];
  const float* nqw = (const float*)d_in[9];
  const float* nkw = (const float*)d_in[10];
  const float* cache_k = (const float*)d_in[11];
  const float* cache_v = (const float*)d_in[12];
  const float* fcos = (const float*)d_in[13];
  const float* fsin = (const float*)d_in[14];
  float* out = (float*)d_out;

  char* ws = (char*)d_ws;
  size_t off = 0;
  auto alloc = [&](size_t bytes) {
    char* p = ws + off;
    off += (bytes + 255) & ~(size_t)255;
    return p;
  };
  const int XN = SEQ * DIM;       // 2,396,160
  const int WN = DIM * DIM;       // 2,359,296
  bf16* xb = (bf16*)alloc((size_t)XN * 2);
  bf16* Wqb = (bf16*)alloc((size_t)WN * 2);
  bf16* Wkb = (bf16*)alloc((size_t)WN * 2);
  bf16* Wvb = (bf16*)alloc((size_t)WN * 2);
  bf16* Wob = (bf16*)alloc((size_t)WN * 2);
  bf16* QhB = (bf16*)alloc((size_t)NH * SEQ * HD * 2);
  bf16* Kcat = (bf16*)alloc((size_t)NH * KVP * HD * 2);
  bf16* Vt = (bf16*)alloc((size_t)NH * HD * KVP * 2);
  bf16* Aout = (bf16*)alloc((size_t)XN * 2);
  float* MLpart = (float*)alloc((size_t)NSPLIT * NH * SEQ * 2 * 4);
  // Opart (written by attn_split) overlays qraw/kraw/vraw (dead after build_vt);
  // NSPLIT*NH*SEQ*HD == 6*XN >= 3*XN.
  float* Opart = (float*)alloc((size_t)NSPLIT * NH * SEQ * HD * 4);
  float* qraw = Opart;
  float* kraw = qraw + XN;
  float* vraw = kraw + XN;

  CastBatch cb;
  cb.src[0] = x;  cb.dst[0] = xb;  cb.n[0] = XN;
  cb.src[1] = Wq; cb.dst[1] = Wqb; cb.n[1] = WN;
  cb.src[2] = Wk; cb.dst[2] = Wkb; cb.n[2] = WN;
  cb.src[3] = Wv; cb.dst[3] = Wvb; cb.n[3] = WN;
  cb.src[4] = Wo; cb.dst[4] = Wob; cb.n[4] = WN;
  castall<<<dim3((XN + 2047) / 2048, 5), 256, 0, stream>>>(cb);

  clear_pad<<<dim3(((KVP - KV) * HD + 255) / 256, NH), 256, 0, stream>>>(Kcat, Vt);

  GemmBatch gqkv;
  gqkv.B[0] = Wqb; gqkv.B[1] = Wkb; gqkv.B[2] = Wvb;
  gqkv.bias[0] = bq; gqkv.bias[1] = bk; gqkv.bias[2] = bv;
  gqkv.C[0] = qraw; gqkv.C[1] = kraw; gqkv.C[2] = vraw;
  gemm_bt<<<dim3(13, 12, 3), 256, 0, stream>>>(xb, gqkv, SEQ);

  norm_rope<<<SEQ, 256, 0, stream>>>(qraw, kraw, nqw, nkw, fcos, fsin, QhB, Kcat);
  build_kcat<<<NEWBASE, 256, 0, stream>>>(cache_k, Kcat);
  build_vt<<<dim3(147, NH), 256, 0, stream>>>(cache_v, vraw, Vt);

  attn_split<<<dim3(NQT * NH * NSPLIT), 256, 0, stream>>>(QhB, Kcat, Vt, Opart, MLpart);
  attn_merge<<<(NH * SEQ + 1) / 2, 256, 0, stream>>>(Opart, MLpart, Aout);

  GemmBatch gout;
  gout.B[0] = Wob; gout.B[1] = Wob; gout.B[2] = Wob;
  gout.bias[0] = bo; gout.bias[1] = bo; gout.bias[2] = bo;
  gout.C[0] = out; gout.C[1] = out; gout.C[2] = out;
  gemm_bt<<<dim3(13, 12, 1), 256, 0, stream>>>(Aout, gout, SEQ);
}

// Round 16
// 302.417 us; speedup vs baseline: 1.1336x; 1.1336x over previous
//
#include <hip/hip_runtime.h>
#include <hip/hip_bf16.h>

typedef __bf16 bf16;
typedef __bf16 bf16x2 __attribute__((ext_vector_type(2)));
typedef __bf16 bf16x4 __attribute__((ext_vector_type(4)));
typedef __bf16 bf16x8 __attribute__((ext_vector_type(8)));
typedef float f32x4 __attribute__((ext_vector_type(4)));
typedef float f32x16 __attribute__((ext_vector_type(16)));
typedef unsigned u32x2 __attribute__((ext_vector_type(2)));

#define DIM 1536
#define NH 12
#define HD 128
#define SEQ 1560
#define KV 9360
#define KVP 9408      // padded to 294*32 so staging never needs clamps
#define SINK 1560
#define NEWBASE 7800  // k_cat rows [7800,9360) are the new tokens
// logits computed in log2 domain: Q pre-scaled by HD^-0.5 * log2(e)
#define QSCALE_L2E (0.08838834764831845f * 1.4426950408889634f)
#define NSPLIT 3
#define CHUNK 3136    // 98 tiles of 32; 3*3136 = 9408 = KVP exactly
#define NT 98
#define KB 32         // keys per tile
#define QBLK 128
#define NQT 13        // ceil(1560/128)

__device__ __forceinline__ void gl_lds16(const void* g, void* l) {
  __builtin_amdgcn_global_load_lds(
      (const __attribute__((address_space(1))) unsigned int*)g,
      (__attribute__((address_space(3))) unsigned int*)l, 16, 0, 0);
}

__device__ __forceinline__ f32x16 mfma32(bf16x8 a, bf16x8 b, f32x16 c) {
  return __builtin_amdgcn_mfma_f32_32x32x16_bf16(a, b, c, 0, 0, 0);
}

// ---------------- fused cast f32 -> bf16 (x + 4 weights) ----------------
struct CastBatch {
  const float* src[5];
  bf16* dst[5];
  int n[5];
};
__global__ __launch_bounds__(256) void castall(CastBatch cb) {
  const float* src = cb.src[blockIdx.y];
  bf16* dst = cb.dst[blockIdx.y];
  int n = cb.n[blockIdx.y];
  int i = (blockIdx.x * 256 + threadIdx.x) * 8;
  if (i < n) {
    float4 a = *(const float4*)(src + i);
    float4 b = *(const float4*)(src + i + 4);
    bf16x8 o;
    o[0] = (bf16)a.x; o[1] = (bf16)a.y; o[2] = (bf16)a.z; o[3] = (bf16)a.w;
    o[4] = (bf16)b.x; o[5] = (bf16)b.y; o[6] = (bf16)b.z; o[7] = (bf16)b.w;
    *(bf16x8*)(dst + i) = o;
  }
}

// ---------------- GEMM: C[M,N] = A[M,K] * B[N,K]^T + bias, f32 out ----------------
struct GemmBatch {
  const bf16* B[3];
  const float* bias[3];
  float* C[3];
};

#define BM 128
#define BN 128
#define BK 32

__global__ __launch_bounds__(256, 2) void gemm_bt(const bf16* __restrict__ A,
                                                  GemmBatch gb, int M) {
  const bf16* Bw = gb.B[blockIdx.z];
  const float* bias = gb.bias[blockIdx.z];
  float* C = gb.C[blockIdx.z];
  int bm = blockIdx.x * BM;
  int bn = blockIdx.y * BN;

  __shared__ bf16 Alds[2][BM][BK];
  __shared__ bf16 Blds[2][BN][BK];

  int t = threadIdx.x;
  int lane = t & 63;
  int wave = t >> 6;
  int wr = wave >> 1, wc = wave & 1;
  int fr = lane & 15;
  int fo = (lane >> 4) * 8;

  f32x4 acc[4][4] = {};

  const int NK = DIM / BK;  // 48
  int colA = (lane & 3) * 8;
  int lrow = lane >> 2;

#define STAGEG(buf, k0)                                                     \
  {                                                                         \
    _Pragma("unroll") for (int p = 0; p < 2; ++p) {                         \
      int rbase = wave * 16 + p * 64;                                       \
      int ga = bm + rbase + lrow;                                           \
      if (ga > M - 1) ga = M - 1;                                           \
      gl_lds16(A + (size_t)ga * DIM + (k0) + colA, &Alds[buf][rbase][0]);   \
      int gbv = bn + rbase + lrow;                                          \
      gl_lds16(Bw + (size_t)gbv * DIM + (k0) + colA, &Blds[buf][rbase][0]); \
    }                                                                       \
  }

  STAGEG(0, 0);
  int cur = 0;
  for (int ks = 0; ks < NK; ++ks) {
    __syncthreads();  // drains vmcnt -> buf[cur] ready
    if (ks + 1 < NK) STAGEG(cur ^ 1, (ks + 1) * BK);
    bf16x8 af[4], bfv[4];
#pragma unroll
    for (int i = 0; i < 4; ++i)
      af[i] = *(const bf16x8*)&Alds[cur][wr * 64 + i * 16 + fr][fo];
#pragma unroll
    for (int j = 0; j < 4; ++j)
      bfv[j] = *(const bf16x8*)&Blds[cur][wc * 64 + j * 16 + fr][fo];
#pragma unroll
    for (int i = 0; i < 4; ++i)
#pragma unroll
      for (int j = 0; j < 4; ++j)
        acc[i][j] = __builtin_amdgcn_mfma_f32_16x16x32_bf16(af[i], bfv[j],
                                                            acc[i][j], 0, 0, 0);
    cur ^= 1;
  }
#undef STAGEG

  int g4 = (lane >> 4) * 4;
#pragma unroll
  for (int i = 0; i < 4; ++i) {
    int mbase = bm + wr * 64 + i * 16 + g4;
#pragma unroll
    for (int j = 0; j < 4; ++j) {
      int col = bn + wc * 64 + j * 16 + fr;
      float bv = bias[col];
#pragma unroll
      for (int r = 0; r < 4; ++r) {
        int m = mbase + r;
        if (m < M) C[(size_t)m * DIM + col] = acc[i][j][r] + bv;
      }
    }
  }
}

// ---------------- RMSNorm + RoPE for q,k ----------------
__global__ __launch_bounds__(256) void norm_rope(
    const float* __restrict__ qraw, const float* __restrict__ kraw,
    const float* __restrict__ nqw, const float* __restrict__ nkw,
    const float* __restrict__ fcos, const float* __restrict__ fsin,
    bf16* __restrict__ Qh, bf16* __restrict__ Kcat) {
  int tok = blockIdx.x;
  int tid = threadIdx.x;
  const float* qr = qraw + (size_t)tok * DIM;
  const float* kr = kraw + (size_t)tok * DIM;
  float sq = 0.f, sk = 0.f;
  for (int c = tid; c < DIM; c += 256) {
    float a = qr[c];
    sq += a * a;
    float b = kr[c];
    sk += b * b;
  }
#pragma unroll
  for (int off = 32; off; off >>= 1) {
    sq += __shfl_down(sq, off);
    sk += __shfl_down(sk, off);
  }
  __shared__ float red[2][4];
  int w = tid >> 6;
  if ((tid & 63) == 0) {
    red[0][w] = sq;
    red[1][w] = sk;
  }
  __syncthreads();
  sq = red[0][0] + red[0][1] + red[0][2] + red[0][3];
  sk = red[1][0] + red[1][1] + red[1][2] + red[1][3];
  float rsq = rsqrtf(sq * (1.0f / DIM) + 1e-6f);
  float rsk = rsqrtf(sk * (1.0f / DIM) + 1e-6f);

  int hrow = tok / 52, wrow = tok % 52;
  for (int p = tid; p < NH * 64; p += 256) {
    int n = p >> 6, i = p & 63;
    int trow = (i < 22) ? 6 : (i < 43 ? hrow : wrow);
    float cs = fcos[trow * 64 + i];
    float sn = fsin[trow * 64 + i];
    int c = n * HD + 2 * i;
    float xr = qr[c] * rsq * nqw[c];
    float xi = qr[c + 1] * rsq * nqw[c + 1];
    bf16x2 qo;
    qo[0] = (bf16)((xr * cs - xi * sn) * QSCALE_L2E);
    qo[1] = (bf16)((xr * sn + xi * cs) * QSCALE_L2E);
    *(bf16x2*)(Qh + ((size_t)n * SEQ + tok) * HD + 2 * i) = qo;
    float yr = kr[c] * rsk * nkw[c];
    float yi = kr[c + 1] * rsk * nkw[c + 1];
    bf16x2 ko;
    ko[0] = (bf16)(yr * cs - yi * sn);
    ko[1] = (bf16)(yr * sn + yi * cs);
    *(bf16x2*)(Kcat + ((size_t)n * KVP + NEWBASE + tok) * HD + 2 * i) = ko;
  }
}

// ---- gather cache_k rows into K_cat; blocks >= NEWBASE zero the pad rows ----
__global__ __launch_bounds__(256) void build_kcat(const float* __restrict__ cache_k,
                                                  bf16* __restrict__ Kcat) {
  int j = blockIdx.x;  // 0..7799 gather, 7800..7847 -> zero pad rows
  if (j >= NEWBASE) {
    int r = KV + (j - NEWBASE);  // 9360..9407
    for (int e = threadIdx.x; e < NH * HD; e += 256) {
      int n = e >> 7, d = e & 127;
      Kcat[((size_t)n * KVP + r) * HD + d] = (bf16)0.f;
    }
    return;
  }
  int src = j < SINK ? j : j + SINK;
  const float* sp = cache_k + (size_t)src * DIM;
  for (int c4 = threadIdx.x; c4 < DIM / 4; c4 += 256) {
    float4 v = *(const float4*)(sp + c4 * 4);
    int c = c4 * 4;
    int n = c >> 7, d = c & 127;
    bf16x4 o;
    o[0] = (bf16)v.x; o[1] = (bf16)v.y; o[2] = (bf16)v.z; o[3] = (bf16)v.w;
    *(bf16x4*)(Kcat + ((size_t)n * KVP + j) * HD + d) = o;
  }
}

// ---- build transposed V: Vt[h][d][j]; pad cols j in [KV,KVP) get zeros ----
__global__ __launch_bounds__(256) void build_vt(const float* __restrict__ cache_v,
                                                const float* __restrict__ vraw,
                                                bf16* __restrict__ Vt) {
  int h = blockIdx.y;
  int j0 = blockIdx.x * 64;
  __shared__ bf16 T[128][72];
  int tid = threadIdx.x;
  for (int idx = tid; idx < 64 * 32; idx += 256) {
    int jl = idx >> 5, s = idx & 31;
    int j = j0 + jl;
    float4 v;
    if (j >= KV) {
      v = make_float4(0.f, 0.f, 0.f, 0.f);
    } else {
      const float* sp;
      if (j < NEWBASE) {
        int srcj = j < SINK ? j : j + SINK;
        sp = cache_v + (size_t)srcj * DIM + h * HD;
      } else {
        sp = vraw + (size_t)(j - NEWBASE) * DIM + h * HD;
      }
      v = *(const float4*)(sp + s * 4);
    }
    T[s * 4 + 0][jl] = (bf16)v.x;
    T[s * 4 + 1][jl] = (bf16)v.y;
    T[s * 4 + 2][jl] = (bf16)v.z;
    T[s * 4 + 3][jl] = (bf16)v.w;
  }
  __syncthreads();
  for (int idx = tid; idx < 128 * 16; idx += 256) {
    int d = idx >> 4, g = idx & 15;
    int j = j0 + g * 4;
    bf16x4 o;
    o[0] = T[d][4 * g];
    o[1] = T[d][4 * g + 1];
    o[2] = T[d][4 * g + 2];
    o[3] = T[d][4 * g + 3];
    *(bf16x4*)(Vt + ((size_t)h * HD + d) * KVP + j) = o;
  }
}

// ---- flash attention: KB=32, T15 two-tile pipeline (QK(t) || SM+PV(t-1)) ----
__global__ __launch_bounds__(256, 2) void attn_split(const bf16* __restrict__ Qh,
                                                     const bf16* __restrict__ Kcat,
                                                     const bf16* __restrict__ Vtg,
                                                     float* __restrict__ Opart,
                                                     float* __restrict__ MLpart) {
  // bijective XCD swizzle (m204): NB = 13*12*3 = 468, q=58, r=4
  int orig = blockIdx.x;
  int xcd = orig & 7, jj = orig >> 3;
  int wgid = (xcd < 4 ? xcd * 59 : 236 + (xcd - 4) * 58) + jj;
  int qt = wgid % NQT;
  int h = (wgid / NQT) % NH;
  int sp = wgid / (NQT * NH);
  int q0 = qt * QBLK;
  int c0 = sp * CHUNK;

  int t = threadIdx.x, lane = t & 63, w = t >> 6;
  int ql = lane & 31, hi = lane >> 5;

  __shared__ __align__(16) bf16 Klds[2][KB * 128];   // 2 x 8 KB
  __shared__ __align__(16) bf16 Vlds[3][128 * KB];   // 3 x 8 KB (PV lags 1 tile)

  // Q fragments (B-operand of 32x32x16): lane holds Q[q=ql][ks*16 + hi*8 + j]
  int qrow = q0 + w * 32 + ql;
  int qcl = qrow < SEQ ? qrow : SEQ - 1;
  const bf16* Qp = Qh + ((size_t)h * SEQ + qcl) * HD + hi * 8;
  bf16x8 qreg[8];
#pragma unroll
  for (int ks = 0; ks < 8; ++ks) qreg[ks] = *(const bf16x8*)(Qp + ks * 16);

  // staging: linear LDS dest (gl_lds), pre-swizzled global source
  int kadd[2], vadd[2];
#pragma unroll
  for (int p = 0; p < 2; ++p) {
    int m = (2 * w + p) * 64 + lane;  // 16B-chunk index, 0..511
    int rK = m >> 4, cK = m & 15;     // K row 0..31, 16 chunks/row
    kadd[p] = rK * HD + (cK ^ (rK & 15)) * 8;
    int dV = m >> 2, cV = m & 3;      // V row(d) 0..127, 4 chunks/row
    vadd[p] = dV * KVP + (cV ^ ((dV >> 1) & 3)) * 8;
  }

  // swizzled LDS read offsets
  int koff[8];
#pragma unroll
  for (int ks = 0; ks < 8; ++ks)
    koff[ks] = ql * 256 + (((ks * 2 + hi) ^ (ql & 15)) * 16);
  int voff[4][2];
#pragma unroll
  for (int db = 0; db < 4; ++db)
#pragma unroll
    for (int ks = 0; ks < 2; ++ks)
      voff[db][ks] = (db * 32 + ql) * 64 + (((ks * 2 + hi) ^ ((ql >> 1) & 3)) * 16);

  const bf16* Khp = Kcat + (size_t)h * KVP * HD;
  const bf16* Vhp = Vtg + (size_t)h * HD * KVP;
  char* Kb = (char*)&Klds[0][0];
  char* Vb = (char*)&Vlds[0][0];

  f32x16 oacc[4] = {};
  float m_q = -1e38f, l_q = 0.f;
  f32x16 sA, sB;
  int vst, vpv;  // rotating V buffer indices (uniform scalars)

#define STAGEK(kbuf, TIs)                                                     \
  {                                                                           \
    const bf16* Ks = Khp + (size_t)(c0 + (TIs)*KB) * HD;                      \
    _Pragma("unroll") for (int p = 0; p < 2; ++p)                             \
        gl_lds16(Ks + kadd[p], Kb + (kbuf)*8192 + w * 2048 + p * 1024);       \
  }
#define STAGEV(vbuf, TIs)                                                     \
  {                                                                           \
    const bf16* Vs = Vhp + (c0 + (TIs)*KB);                                   \
    _Pragma("unroll") for (int p = 0; p < 2; ++p)                             \
        gl_lds16(Vs + vadd[p], Vb + (vbuf)*8192 + w * 2048 + p * 1024);       \
  }

  // QK for tile TI from K buffer KQK -> SC (with tail mask)
#define QKT(SC, KQK, TI)                                                      \
  {                                                                           \
    const char* Kc = Kb + (KQK)*8192;                                         \
    f32x16 stmp = {};                                                         \
    __builtin_amdgcn_s_setprio(1);                                            \
    _Pragma("unroll") for (int ks = 0; ks < 8; ++ks)                          \
        stmp = mfma32(*(const bf16x8*)(Kc + koff[ks]), qreg[ks], stmp);       \
    __builtin_amdgcn_s_setprio(0);                                            \
    int j0m = c0 + (TI)*KB;                                                   \
    if (j0m + KB > KV) {                                                      \
      _Pragma("unroll") for (int reg = 0; reg < 16; ++reg) {                  \
        int kk = (reg & 3) + 8 * (reg >> 2) + 4 * hi;                         \
        if (j0m + kk >= KV) stmp[reg] = -1e38f;                               \
      }                                                                       \
    }                                                                         \
    SC = stmp;                                                                \
  }

  // softmax+pack of SP (prev tile) + PV from V buffer vpv
#define SMPV(SP)                                                              \
  {                                                                           \
    float m8[8];                                                              \
    _Pragma("unroll") for (int r = 0; r < 8; ++r)                             \
        m8[r] = fmaxf(SP[r], SP[r + 8]);                                      \
    float mx = fmaxf(fmaxf(fmaxf(m8[0], m8[4]), fmaxf(m8[1], m8[5])),         \
                     fmaxf(fmaxf(m8[2], m8[6]), fmaxf(m8[3], m8[7])));        \
    mx = fmaxf(mx, __shfl_xor(mx, 32));                                       \
    if (__any(mx - m_q > 8.f)) {                                              \
      float mnew = fmaxf(m_q, mx);                                            \
      float corr = exp2f(m_q - mnew);                                         \
      m_q = mnew;                                                             \
      l_q *= corr;                                                            \
      _Pragma("unroll") for (int reg = 0; reg < 16; ++reg) {                  \
        int qsrc = (reg & 3) + 8 * (reg >> 2) + 4 * hi;                       \
        float c = __shfl(corr, qsrc);                                         \
        _Pragma("unroll") for (int db = 0; db < 4; ++db) oacc[db][reg] *= c;  \
      }                                                                       \
    }                                                                         \
    _Pragma("unroll") for (int r = 0; r < 16; ++r)                            \
        SP[r] = exp2f(SP[r] - m_q);                                           \
    float t8[8];                                                              \
    _Pragma("unroll") for (int r = 0; r < 8; ++r) t8[r] = SP[r] + SP[r + 8];  \
    float sum = ((t8[0] + t8[4]) + (t8[1] + t8[5])) +                         \
                ((t8[2] + t8[6]) + (t8[3] + t8[7]));                          \
    sum += __shfl_xor(sum, 32);                                               \
    l_q += sum;                                                               \
    bf16x8 pa[2];                                                             \
    _Pragma("unroll") for (int ks = 0; ks < 2; ++ks) {                        \
      const int r0 = ks * 8;                                                  \
      bf16x2 p0, p1, p2, p3;                                                  \
      p0[0] = (bf16)SP[r0 + 0]; p0[1] = (bf16)SP[r0 + 1];                     \
      p1[0] = (bf16)SP[r0 + 2]; p1[1] = (bf16)SP[r0 + 3];                     \
      p2[0] = (bf16)SP[r0 + 4]; p2[1] = (bf16)SP[r0 + 5];                     \
      p3[0] = (bf16)SP[r0 + 6]; p3[1] = (bf16)SP[r0 + 7];                     \
      unsigned x0 = __builtin_bit_cast(unsigned, p0);                         \
      unsigned x1 = __builtin_bit_cast(unsigned, p1);                         \
      unsigned y0 = __builtin_bit_cast(unsigned, p2);                         \
      unsigned y1 = __builtin_bit_cast(unsigned, p3);                         \
      u32x2 r0v = __builtin_amdgcn_permlane32_swap(x0, y0, false, false);     \
      u32x2 r1v = __builtin_amdgcn_permlane32_swap(x1, y1, false, false);     \
      int4 tmp;                                                               \
      tmp.x = (int)r0v[0];                                                    \
      tmp.y = (int)r1v[0];                                                    \
      tmp.z = (int)r0v[1];                                                    \
      tmp.w = (int)r1v[1];                                                    \
      pa[ks] = __builtin_bit_cast(bf16x8, tmp);                               \
    }                                                                         \
    const char* Vc = Vb + vpv * 8192;                                         \
    __builtin_amdgcn_s_setprio(1);                                            \
    _Pragma("unroll") for (int db = 0; db < 4; ++db)                          \
        _Pragma("unroll") for (int ks = 0; ks < 2; ++ks)                      \
            oacc[db] = mfma32(pa[ks], *(const bf16x8*)(Vc + voff[db][ks]),    \
                              oacc[db]);                                      \
    __builtin_amdgcn_s_setprio(0);                                            \
  }

  // full pipelined body for tile TI: stage(TI+1), QK(TI) || SM+PV(TI-1)
#define BODY(TI, SC, SP, KQK, KST)                                            \
  {                                                                           \
    if ((TI) + 1 < NT) {                                                      \
      STAGEK(KST, (TI) + 1);                                                  \
      STAGEV(vst, (TI) + 1);                                                  \
    }                                                                         \
    QKT(SC, KQK, TI);                                                         \
    SMPV(SP);                                                                 \
    __syncthreads();                                                          \
    vst = vst == 2 ? 0 : vst + 1;                                             \
    vpv = vpv == 2 ? 0 : vpv + 1;                                             \
  }

  // prologue: tile0 -> K0,V0
  STAGEK(0, 0);
  STAGEV(0, 0);
  __syncthreads();
  // body 0 (tile 0, no prev): stage tile1 -> K1,V1; QK(0)->sA
  STAGEK(1, 1);
  STAGEV(1, 1);
  QKT(sA, 0, 0);
  __syncthreads();
  vst = 2;  // body1 stages tile2 -> V2
  vpv = 0;  // body1's PV consumes tile0 -> V0
  // body 1 (tile 1): QK(1)->sB from K1, stage tile2 -> K0; SM+PV(tile0)
  BODY(1, sB, sA, 1, 0);
  // main loop: tiles 2..97 (96 bodies, unroll 2 for sA/sB ping-pong)
#pragma unroll 1
  for (int it = 0; it < 48; ++it) {
    int ti = 2 + 2 * it;
    BODY(ti, sA, sB, 0, 1);      // QK from K[ti%2=0], stage K[(ti+1)%2=1]
    BODY(ti + 1, sB, sA, 1, 0);  // QK from K1, stage K0
  }
  // epilogue: SM+PV for tile 97 (sB); vpv rotated to 97%3 = 1
  SMPV(sB);
#undef BODY
#undef SMPV
#undef QKT
#undef STAGEV
#undef STAGEK

  // store unnormalized partials: lane holds O[q=...reg...][d=db*32+ql]
  float* Oh = Opart + ((size_t)sp * NH + h) * SEQ * HD;
  float* MLh = MLpart + ((size_t)sp * NH + h) * SEQ * 2;
#pragma unroll
  for (int reg = 0; reg < 16; ++reg) {
    int q = q0 + w * 32 + (reg & 3) + 8 * (reg >> 2) + 4 * hi;
    if (q >= SEQ) continue;
#pragma unroll
    for (int db = 0; db < 4; ++db)
      Oh[(size_t)q * HD + db * 32 + ql] = oacc[db][reg];
  }
  if (lane < 32) {
    int q = q0 + w * 32 + ql;
    if (q < SEQ) {
      MLh[q * 2 + 0] = m_q;
      MLh[q * 2 + 1] = l_q;
    }
  }
}

// ---------------- merge split partials (log2-domain m) ----------------
__global__ __launch_bounds__(256) void attn_merge(const float* __restrict__ Opart,
                                                  const float* __restrict__ MLpart,
                                                  bf16* __restrict__ Aout) {
  int idx = blockIdx.x * 2 + (threadIdx.x >> 7);
  if (idx >= NH * SEQ) return;
  int d = threadIdx.x & 127;
  int h = idx / SEQ, q = idx % SEQ;
  float m[NSPLIT];
  float M = -1e38f;
#pragma unroll
  for (int s = 0; s < NSPLIT; ++s) {
    m[s] = MLpart[(((size_t)s * NH + h) * SEQ + q) * 2];
    M = fmaxf(M, m[s]);
  }
  float L = 0.f, o = 0.f;
#pragma unroll
  for (int s = 0; s < NSPLIT; ++s) {
    float wgt = exp2f(m[s] - M);
    L += MLpart[(((size_t)s * NH + h) * SEQ + q) * 2 + 1] * wgt;
    o += Opart[((((size_t)s * NH + h) * SEQ + q)) * HD + d] * wgt;
  }
  Aout[(size_t)q * DIM + h * HD + d] = (bf16)(o / L);
}

// ---------------- host ----------------
extern "C" void kernel_launch(void* const* d_in, const int* in_sizes, int n_in,
                              void* d_out, int out_size, void* d_ws, size_t ws_size,
                              hipStream_t stream) {
  const float* x = (const float*)d_in[0];
  const float* Wq = (const float*)d_in[1];
  const float* bq = (const float*)d_in[2];
  const float* Wk = (const float*)d_in[3];
  const float* bk = (const float*)d_in[4];
  const float* Wv = (const float*)d_in[5];
  const float* bv = (const float*)d_in[6];
  const float* Wo = (const float*)d_in[7];
  const float* bo = (const float*)d_in[8];
  const float* nqw = (const float*)d_in[9];
  const float* nkw = (const float*)d_in[10];
  const float* cache_k = (const float*)d_in[11];
  const float* cache_v = (const float*)d_in[12];
  const float* fcos = (const float*)d_in[13];
  const float* fsin = (const float*)d_in[14];
  float* out = (float*)d_out;

  char* ws = (char*)d_ws;
  size_t off = 0;
  auto alloc = [&](size_t bytes) {
    char* p = ws + off;
    off += (bytes + 255) & ~(size_t)255;
    return p;
  };
  const int XN = SEQ * DIM;       // 2,396,160
  const int WN = DIM * DIM;       // 2,359,296
  bf16* xb = (bf16*)alloc((size_t)XN * 2);
  bf16* Wqb = (bf16*)alloc((size_t)WN * 2);
  bf16* Wkb = (bf16*)alloc((size_t)WN * 2);
  bf16* Wvb = (bf16*)alloc((size_t)WN * 2);
  bf16* Wob = (bf16*)alloc((size_t)WN * 2);
  bf16* QhB = (bf16*)alloc((size_t)NH * SEQ * HD * 2);
  bf16* Kcat = (bf16*)alloc((size_t)NH * KVP * HD * 2);
  bf16* Vt = (bf16*)alloc((size_t)NH * HD * KVP * 2);
  bf16* Aout = (bf16*)alloc((size_t)XN * 2);
  float* MLpart = (float*)alloc((size_t)NSPLIT * NH * SEQ * 2 * 4);
  // Opart (written by attn_split) overlays qraw/kraw/vraw (dead after build_vt);
  // NSPLIT*NH*SEQ*HD == 3*XN exactly.
  float* Opart = (float*)alloc((size_t)NSPLIT * NH * SEQ * HD * 4);
  float* qraw = Opart;
  float* kraw = qraw + XN;
  float* vraw = kraw + XN;

  CastBatch cb;
  cb.src[0] = x;  cb.dst[0] = xb;  cb.n[0] = XN;
  cb.src[1] = Wq; cb.dst[1] = Wqb; cb.n[1] = WN;
  cb.src[2] = Wk; cb.dst[2] = Wkb; cb.n[2] = WN;
  cb.src[3] = Wv; cb.dst[3] = Wvb; cb.n[3] = WN;
  cb.src[4] = Wo; cb.dst[4] = Wob; cb.n[4] = WN;
  castall<<<dim3((XN + 2047) / 2048, 5), 256, 0, stream>>>(cb);

  GemmBatch gqkv;
  gqkv.B[0] = Wqb; gqkv.B[1] = Wkb; gqkv.B[2] = Wvb;
  gqkv.bias[0] = bq; gqkv.bias[1] = bk; gqkv.bias[2] = bv;
  gqkv.C[0] = qraw; gqkv.C[1] = kraw; gqkv.C[2] = vraw;
  gemm_bt<<<dim3(13, 12, 3), 256, 0, stream>>>(xb, gqkv, SEQ);

  norm_rope<<<SEQ, 256, 0, stream>>>(qraw, kraw, nqw, nkw, fcos, fsin, QhB, Kcat);
  build_kcat<<<NEWBASE + (KVP - KV), 256, 0, stream>>>(cache_k, Kcat);
  build_vt<<<dim3(147, NH), 256, 0, stream>>>(cache_v, vraw, Vt);

  attn_split<<<dim3(NQT * NH * NSPLIT), 256, 0, stream>>>(QhB, Kcat, Vt, Opart, MLpart);
  attn_merge<<<(NH * SEQ + 1) / 2, 256, 0, stream>>>(Opart, MLpart, Aout);

  GemmBatch gout;
  gout.B[0] = Wob; gout.B[1] = Wob; gout.B[2] = Wob;
  gout.bias[0] = bo; gout.bias[1] = bo; gout.bias[2] = bo;
  gout.C[0] = out; gout.C[1] = out; gout.C[2] = out;
  gemm_bt<<<dim3(13, 12, 1), 256, 0, stream>>>(Aout, gout, SEQ);
}

// Round 17
// 289.421 us; speedup vs baseline: 1.1845x; 1.0449x over previous
//
#include <hip/hip_runtime.h>
#include <hip/hip_bf16.h>

typedef __bf16 bf16;
typedef __bf16 bf16x2 __attribute__((ext_vector_type(2)));
typedef __bf16 bf16x4 __attribute__((ext_vector_type(4)));
typedef __bf16 bf16x8 __attribute__((ext_vector_type(8)));
typedef float f32x4 __attribute__((ext_vector_type(4)));
typedef float f32x16 __attribute__((ext_vector_type(16)));
typedef unsigned u32x2 __attribute__((ext_vector_type(2)));

#define DIM 1536
#define NH 12
#define HD 128
#define SEQ 1560
#define KV 9360
#define KVP 9408      // padded to 294*32 so staging never needs clamps
#define SINK 1560
#define NEWBASE 7800  // k_cat rows [7800,9360) are the new tokens
// logits computed in log2 domain: Q pre-scaled by HD^-0.5 * log2(e)
#define QSCALE_L2E (0.08838834764831845f * 1.4426950408889634f)
#define NSPLIT 3
#define CHUNK 3136    // 98 tiles of 32; 3*3136 = 9408 = KVP exactly
#define NT 98
#define KB 32         // keys per tile
#define QBLK 128
#define NQT 13        // ceil(1560/128)

__device__ __forceinline__ void gl_lds16(const void* g, void* l) {
  __builtin_amdgcn_global_load_lds(
      (const __attribute__((address_space(1))) unsigned int*)g,
      (__attribute__((address_space(3))) unsigned int*)l, 16, 0, 0);
}

__device__ __forceinline__ f32x16 mfma32(bf16x8 a, bf16x8 b, f32x16 c) {
  return __builtin_amdgcn_mfma_f32_32x32x16_bf16(a, b, c, 0, 0, 0);
}

// ---------------- fused cast f32 -> bf16 (x + 4 weights) ----------------
struct CastBatch {
  const float* src[5];
  bf16* dst[5];
  int n[5];
};
__global__ __launch_bounds__(256) void castall(CastBatch cb) {
  const float* src = cb.src[blockIdx.y];
  bf16* dst = cb.dst[blockIdx.y];
  int n = cb.n[blockIdx.y];
  int i = (blockIdx.x * 256 + threadIdx.x) * 8;
  if (i < n) {
    float4 a = *(const float4*)(src + i);
    float4 b = *(const float4*)(src + i + 4);
    bf16x8 o;
    o[0] = (bf16)a.x; o[1] = (bf16)a.y; o[2] = (bf16)a.z; o[3] = (bf16)a.w;
    o[4] = (bf16)b.x; o[5] = (bf16)b.y; o[6] = (bf16)b.z; o[7] = (bf16)b.w;
    *(bf16x8*)(dst + i) = o;
  }
}

// ---------------- GEMM: C[M,N] = A[M,K] * B[N,K]^T + bias, f32 out ----------------
struct GemmBatch {
  const bf16* B[3];
  const float* bias[3];
  float* C[3];
};

#define BM 128
#define BN 128
#define BK 32

__global__ __launch_bounds__(256, 2) void gemm_bt(const bf16* __restrict__ A,
                                                  GemmBatch gb, int M) {
  const bf16* Bw = gb.B[blockIdx.z];
  const float* bias = gb.bias[blockIdx.z];
  float* C = gb.C[blockIdx.z];
  int bm = blockIdx.x * BM;
  int bn = blockIdx.y * BN;

  __shared__ bf16 Alds[2][BM][BK];
  __shared__ bf16 Blds[2][BN][BK];

  int t = threadIdx.x;
  int lane = t & 63;
  int wave = t >> 6;
  int wr = wave >> 1, wc = wave & 1;
  int fr = lane & 15;
  int fo = (lane >> 4) * 8;

  f32x4 acc[4][4] = {};

  const int NK = DIM / BK;  // 48
  int colA = (lane & 3) * 8;
  int lrow = lane >> 2;

#define STAGEG(buf, k0)                                                     \
  {                                                                         \
    _Pragma("unroll") for (int p = 0; p < 2; ++p) {                         \
      int rbase = wave * 16 + p * 64;                                       \
      int ga = bm + rbase + lrow;                                           \
      if (ga > M - 1) ga = M - 1;                                           \
      gl_lds16(A + (size_t)ga * DIM + (k0) + colA, &Alds[buf][rbase][0]);   \
      int gbv = bn + rbase + lrow;                                          \
      gl_lds16(Bw + (size_t)gbv * DIM + (k0) + colA, &Blds[buf][rbase][0]); \
    }                                                                       \
  }

  STAGEG(0, 0);
  int cur = 0;
  for (int ks = 0; ks < NK; ++ks) {
    __syncthreads();  // drains vmcnt -> buf[cur] ready
    if (ks + 1 < NK) STAGEG(cur ^ 1, (ks + 1) * BK);
    bf16x8 af[4], bfv[4];
#pragma unroll
    for (int i = 0; i < 4; ++i)
      af[i] = *(const bf16x8*)&Alds[cur][wr * 64 + i * 16 + fr][fo];
#pragma unroll
    for (int j = 0; j < 4; ++j)
      bfv[j] = *(const bf16x8*)&Blds[cur][wc * 64 + j * 16 + fr][fo];
#pragma unroll
    for (int i = 0; i < 4; ++i)
#pragma unroll
      for (int j = 0; j < 4; ++j)
        acc[i][j] = __builtin_amdgcn_mfma_f32_16x16x32_bf16(af[i], bfv[j],
                                                            acc[i][j], 0, 0, 0);
    cur ^= 1;
  }
#undef STAGEG

  int g4 = (lane >> 4) * 4;
#pragma unroll
  for (int i = 0; i < 4; ++i) {
    int mbase = bm + wr * 64 + i * 16 + g4;
#pragma unroll
    for (int j = 0; j < 4; ++j) {
      int col = bn + wc * 64 + j * 16 + fr;
      float bv = bias[col];
#pragma unroll
      for (int r = 0; r < 4; ++r) {
        int m = mbase + r;
        if (m < M) C[(size_t)m * DIM + col] = acc[i][j][r] + bv;
      }
    }
  }
}

// ---------------- RMSNorm + RoPE for q,k ----------------
__global__ __launch_bounds__(256) void norm_rope(
    const float* __restrict__ qraw, const float* __restrict__ kraw,
    const float* __restrict__ nqw, const float* __restrict__ nkw,
    const float* __restrict__ fcos, const float* __restrict__ fsin,
    bf16* __restrict__ Qh, bf16* __restrict__ Kcat) {
  int tok = blockIdx.x;
  int tid = threadIdx.x;
  const float* qr = qraw + (size_t)tok * DIM;
  const float* kr = kraw + (size_t)tok * DIM;
  float sq = 0.f, sk = 0.f;
  for (int c = tid; c < DIM; c += 256) {
    float a = qr[c];
    sq += a * a;
    float b = kr[c];
    sk += b * b;
  }
#pragma unroll
  for (int off = 32; off; off >>= 1) {
    sq += __shfl_down(sq, off);
    sk += __shfl_down(sk, off);
  }
  __shared__ float red[2][4];
  int w = tid >> 6;
  if ((tid & 63) == 0) {
    red[0][w] = sq;
    red[1][w] = sk;
  }
  __syncthreads();
  sq = red[0][0] + red[0][1] + red[0][2] + red[0][3];
  sk = red[1][0] + red[1][1] + red[1][2] + red[1][3];
  float rsq = rsqrtf(sq * (1.0f / DIM) + 1e-6f);
  float rsk = rsqrtf(sk * (1.0f / DIM) + 1e-6f);

  int hrow = tok / 52, wrow = tok % 52;
  for (int p = tid; p < NH * 64; p += 256) {
    int n = p >> 6, i = p & 63;
    int trow = (i < 22) ? 6 : (i < 43 ? hrow : wrow);
    float cs = fcos[trow * 64 + i];
    float sn = fsin[trow * 64 + i];
    int c = n * HD + 2 * i;
    float xr = qr[c] * rsq * nqw[c];
    float xi = qr[c + 1] * rsq * nqw[c + 1];
    bf16x2 qo;
    qo[0] = (bf16)((xr * cs - xi * sn) * QSCALE_L2E);
    qo[1] = (bf16)((xr * sn + xi * cs) * QSCALE_L2E);
    *(bf16x2*)(Qh + ((size_t)n * SEQ + tok) * HD + 2 * i) = qo;
    float yr = kr[c] * rsk * nkw[c];
    float yi = kr[c + 1] * rsk * nkw[c + 1];
    bf16x2 ko;
    ko[0] = (bf16)(yr * cs - yi * sn);
    ko[1] = (bf16)(yr * sn + yi * cs);
    *(bf16x2*)(Kcat + ((size_t)n * KVP + NEWBASE + tok) * HD + 2 * i) = ko;
  }
}

// ---- gather cache_k rows into K_cat; blocks >= NEWBASE zero the pad rows ----
__global__ __launch_bounds__(256) void build_kcat(const float* __restrict__ cache_k,
                                                  bf16* __restrict__ Kcat) {
  int j = blockIdx.x;  // 0..7799 gather, 7800..7847 -> zero pad rows
  if (j >= NEWBASE) {
    int r = KV + (j - NEWBASE);  // 9360..9407
    for (int e = threadIdx.x; e < NH * HD; e += 256) {
      int n = e >> 7, d = e & 127;
      Kcat[((size_t)n * KVP + r) * HD + d] = (bf16)0.f;
    }
    return;
  }
  int src = j < SINK ? j : j + SINK;
  const float* sp = cache_k + (size_t)src * DIM;
  for (int c4 = threadIdx.x; c4 < DIM / 4; c4 += 256) {
    float4 v = *(const float4*)(sp + c4 * 4);
    int c = c4 * 4;
    int n = c >> 7, d = c & 127;
    bf16x4 o;
    o[0] = (bf16)v.x; o[1] = (bf16)v.y; o[2] = (bf16)v.z; o[3] = (bf16)v.w;
    *(bf16x4*)(Kcat + ((size_t)n * KVP + j) * HD + d) = o;
  }
}

// ---- build transposed V: Vt[h][d][j]; pad cols j in [KV,KVP) get zeros ----
__global__ __launch_bounds__(256) void build_vt(const float* __restrict__ cache_v,
                                                const float* __restrict__ vraw,
                                                bf16* __restrict__ Vt) {
  int h = blockIdx.y;
  int j0 = blockIdx.x * 64;
  __shared__ bf16 T[128][72];
  int tid = threadIdx.x;
  for (int idx = tid; idx < 64 * 32; idx += 256) {
    int jl = idx >> 5, s = idx & 31;
    int j = j0 + jl;
    float4 v;
    if (j >= KV) {
      v = make_float4(0.f, 0.f, 0.f, 0.f);
    } else {
      const float* sp;
      if (j < NEWBASE) {
        int srcj = j < SINK ? j : j + SINK;
        sp = cache_v + (size_t)srcj * DIM + h * HD;
      } else {
        sp = vraw + (size_t)(j - NEWBASE) * DIM + h * HD;
      }
      v = *(const float4*)(sp + s * 4);
    }
    T[s * 4 + 0][jl] = (bf16)v.x;
    T[s * 4 + 1][jl] = (bf16)v.y;
    T[s * 4 + 2][jl] = (bf16)v.z;
    T[s * 4 + 3][jl] = (bf16)v.w;
  }
  __syncthreads();
  for (int idx = tid; idx < 128 * 16; idx += 256) {
    int d = idx >> 4, g = idx & 15;
    int j = j0 + g * 4;
    bf16x4 o;
    o[0] = T[d][4 * g];
    o[1] = T[d][4 * g + 1];
    o[2] = T[d][4 * g + 2];
    o[3] = T[d][4 * g + 3];
    *(bf16x4*)(Vt + ((size_t)h * HD + d) * KVP + j) = o;
  }
}

// ---- flash attention: KB=32, T15 pipeline, FIXED-m softmax (no online max) ----
// Safe: logits in log2 domain have |s| << 127 for RMSNorm'd inputs, so
// exp2(s) never overflows f32; P <= 2^16 fits bf16 with full relative precision.
__global__ __launch_bounds__(256, 2) void attn_split(const bf16* __restrict__ Qh,
                                                     const bf16* __restrict__ Kcat,
                                                     const bf16* __restrict__ Vtg,
                                                     float* __restrict__ Opart,
                                                     float* __restrict__ MLpart) {
  // bijective XCD swizzle (m204): NB = 13*12*3 = 468, q=58, r=4
  int orig = blockIdx.x;
  int xcd = orig & 7, jj = orig >> 3;
  int wgid = (xcd < 4 ? xcd * 59 : 236 + (xcd - 4) * 58) + jj;
  int qt = wgid % NQT;
  int h = (wgid / NQT) % NH;
  int sp = wgid / (NQT * NH);
  int q0 = qt * QBLK;
  int c0 = sp * CHUNK;

  int t = threadIdx.x, lane = t & 63, w = t >> 6;
  int ql = lane & 31, hi = lane >> 5;

  __shared__ __align__(16) bf16 Klds[2][KB * 128];   // 2 x 8 KB
  __shared__ __align__(16) bf16 Vlds[3][128 * KB];   // 3 x 8 KB (PV lags 1 tile)

  // Q fragments (B-operand of 32x32x16): lane holds Q[q=ql][ks*16 + hi*8 + j]
  int qrow = q0 + w * 32 + ql;
  int qcl = qrow < SEQ ? qrow : SEQ - 1;
  const bf16* Qp = Qh + ((size_t)h * SEQ + qcl) * HD + hi * 8;
  bf16x8 qreg[8];
#pragma unroll
  for (int ks = 0; ks < 8; ++ks) qreg[ks] = *(const bf16x8*)(Qp + ks * 16);

  // staging: linear LDS dest (gl_lds), pre-swizzled global source
  int kadd[2], vadd[2];
#pragma unroll
  for (int p = 0; p < 2; ++p) {
    int m = (2 * w + p) * 64 + lane;  // 16B-chunk index, 0..511
    int rK = m >> 4, cK = m & 15;     // K row 0..31, 16 chunks/row
    kadd[p] = rK * HD + (cK ^ (rK & 15)) * 8;
    int dV = m >> 2, cV = m & 3;      // V row(d) 0..127, 4 chunks/row
    vadd[p] = dV * KVP + (cV ^ ((dV >> 1) & 3)) * 8;
  }

  // swizzled LDS read offsets
  int koff[8];
#pragma unroll
  for (int ks = 0; ks < 8; ++ks)
    koff[ks] = ql * 256 + (((ks * 2 + hi) ^ (ql & 15)) * 16);
  int voff[4][2];
#pragma unroll
  for (int db = 0; db < 4; ++db)
#pragma unroll
    for (int ks = 0; ks < 2; ++ks)
      voff[db][ks] = (db * 32 + ql) * 64 + (((ks * 2 + hi) ^ ((ql >> 1) & 3)) * 16);

  const bf16* Khp = Kcat + (size_t)h * KVP * HD;
  const bf16* Vhp = Vtg + (size_t)h * HD * KVP;
  char* Kb = (char*)&Klds[0][0];
  char* Vb = (char*)&Vlds[0][0];

  f32x16 oacc[4] = {};
  float l_q = 0.f;
  f32x16 sA, sB;
  int vst, vpv;  // rotating V buffer indices (uniform scalars)

#define STAGEK(kbuf, TIs)                                                     \
  {                                                                           \
    const bf16* Ks = Khp + (size_t)(c0 + (TIs)*KB) * HD;                      \
    _Pragma("unroll") for (int p = 0; p < 2; ++p)                             \
        gl_lds16(Ks + kadd[p], Kb + (kbuf)*8192 + w * 2048 + p * 1024);       \
  }
#define STAGEV(vbuf, TIs)                                                     \
  {                                                                           \
    const bf16* Vs = Vhp + (c0 + (TIs)*KB);                                   \
    _Pragma("unroll") for (int p = 0; p < 2; ++p)                             \
        gl_lds16(Vs + vadd[p], Vb + (vbuf)*8192 + w * 2048 + p * 1024);       \
  }

  // QK for tile TI from K buffer KQK -> SC (with tail mask)
#define QKT(SC, KQK, TI)                                                      \
  {                                                                           \
    const char* Kc = Kb + (KQK)*8192;                                         \
    f32x16 stmp = {};                                                         \
    __builtin_amdgcn_s_setprio(1);                                            \
    _Pragma("unroll") for (int ks = 0; ks < 8; ++ks)                          \
        stmp = mfma32(*(const bf16x8*)(Kc + koff[ks]), qreg[ks], stmp);       \
    __builtin_amdgcn_s_setprio(0);                                            \
    int j0m = c0 + (TI)*KB;                                                   \
    if (j0m + KB > KV) {                                                      \
      _Pragma("unroll") for (int reg = 0; reg < 16; ++reg) {                  \
        int kk = (reg & 3) + 8 * (reg >> 2) + 4 * hi;                         \
        if (j0m + kk >= KV) stmp[reg] = -1e38f;                               \
      }                                                                       \
    }                                                                         \
    SC = stmp;                                                                \
  }

  // softmax (fixed m = 0) + pack of SP (prev tile) + PV from V buffer vpv
#define SMPV(SP)                                                              \
  {                                                                           \
    _Pragma("unroll") for (int r = 0; r < 16; ++r)                            \
        SP[r] = exp2f(SP[r]);                                                 \
    float t8[8];                                                              \
    _Pragma("unroll") for (int r = 0; r < 8; ++r) t8[r] = SP[r] + SP[r + 8];  \
    float sum = ((t8[0] + t8[4]) + (t8[1] + t8[5])) +                         \
                ((t8[2] + t8[6]) + (t8[3] + t8[7]));                          \
    sum += __shfl_xor(sum, 32);                                               \
    l_q += sum;                                                               \
    bf16x8 pa[2];                                                             \
    _Pragma("unroll") for (int ks = 0; ks < 2; ++ks) {                        \
      const int r0 = ks * 8;                                                  \
      bf16x2 p0, p1, p2, p3;                                                  \
      p0[0] = (bf16)SP[r0 + 0]; p0[1] = (bf16)SP[r0 + 1];                     \
      p1[0] = (bf16)SP[r0 + 2]; p1[1] = (bf16)SP[r0 + 3];                     \
      p2[0] = (bf16)SP[r0 + 4]; p2[1] = (bf16)SP[r0 + 5];                     \
      p3[0] = (bf16)SP[r0 + 6]; p3[1] = (bf16)SP[r0 + 7];                     \
      unsigned x0 = __builtin_bit_cast(unsigned, p0);                         \
      unsigned x1 = __builtin_bit_cast(unsigned, p1);                         \
      unsigned y0 = __builtin_bit_cast(unsigned, p2);                         \
      unsigned y1 = __builtin_bit_cast(unsigned, p3);                         \
      u32x2 r0v = __builtin_amdgcn_permlane32_swap(x0, y0, false, false);     \
      u32x2 r1v = __builtin_amdgcn_permlane32_swap(x1, y1, false, false);     \
      int4 tmp;                                                               \
      tmp.x = (int)r0v[0];                                                    \
      tmp.y = (int)r1v[0];                                                    \
      tmp.z = (int)r0v[1];                                                    \
      tmp.w = (int)r1v[1];                                                    \
      pa[ks] = __builtin_bit_cast(bf16x8, tmp);                               \
    }                                                                         \
    const char* Vc = Vb + vpv * 8192;                                         \
    __builtin_amdgcn_s_setprio(1);                                            \
    _Pragma("unroll") for (int db = 0; db < 4; ++db)                          \
        _Pragma("unroll") for (int ks = 0; ks < 2; ++ks)                      \
            oacc[db] = mfma32(pa[ks], *(const bf16x8*)(Vc + voff[db][ks]),    \
                              oacc[db]);                                      \
    __builtin_amdgcn_s_setprio(0);                                            \
  }

  // full pipelined body for tile TI: stage(TI+1), QK(TI) || SM+PV(TI-1)
#define BODY(TI, SC, SP, KQK, KST)                                            \
  {                                                                           \
    if ((TI) + 1 < NT) {                                                      \
      STAGEK(KST, (TI) + 1);                                                  \
      STAGEV(vst, (TI) + 1);                                                  \
    }                                                                         \
    QKT(SC, KQK, TI);                                                         \
    SMPV(SP);                                                                 \
    __syncthreads();                                                          \
    vst = vst == 2 ? 0 : vst + 1;                                             \
    vpv = vpv == 2 ? 0 : vpv + 1;                                             \
  }

  // prologue: tile0 -> K0,V0
  STAGEK(0, 0);
  STAGEV(0, 0);
  __syncthreads();
  // body 0 (tile 0, no prev): stage tile1 -> K1,V1; QK(0)->sA
  STAGEK(1, 1);
  STAGEV(1, 1);
  QKT(sA, 0, 0);
  __syncthreads();
  vst = 2;  // body1 stages tile2 -> V2
  vpv = 0;  // body1's PV consumes tile0 -> V0
  // body 1 (tile 1): QK(1)->sB from K1, stage tile2 -> K0; SM+PV(tile0)
  BODY(1, sB, sA, 1, 0);
  // main loop: tiles 2..97 (96 bodies, unroll 2 for sA/sB ping-pong)
#pragma unroll 1
  for (int it = 0; it < 48; ++it) {
    int ti = 2 + 2 * it;
    BODY(ti, sA, sB, 0, 1);      // QK from K[ti%2=0], stage K[(ti+1)%2=1]
    BODY(ti + 1, sB, sA, 1, 0);  // QK from K1, stage K0
  }
  // epilogue: SM+PV for tile 97 (sB); vpv rotated to 97%3 = 1
  SMPV(sB);
#undef BODY
#undef SMPV
#undef QKT
#undef STAGEV
#undef STAGEK

  // store unnormalized partials: lane holds O[q=...reg...][d=db*32+ql]
  float* Oh = Opart + ((size_t)sp * NH + h) * SEQ * HD;
  float* MLh = MLpart + ((size_t)sp * NH + h) * SEQ * 2;
#pragma unroll
  for (int reg = 0; reg < 16; ++reg) {
    int q = q0 + w * 32 + (reg & 3) + 8 * (reg >> 2) + 4 * hi;
    if (q >= SEQ) continue;
#pragma unroll
    for (int db = 0; db < 4; ++db)
      Oh[(size_t)q * HD + db * 32 + ql] = oacc[db][reg];
  }
  if (lane < 32) {
    int q = q0 + w * 32 + ql;
    if (q < SEQ) {
      MLh[q * 2 + 0] = 0.f;   // fixed m = 0 (log2 domain)
      MLh[q * 2 + 1] = l_q;
    }
  }
}

// ---------------- merge split partials (log2-domain m) ----------------
__global__ __launch_bounds__(256) void attn_merge(const float* __restrict__ Opart,
                                                  const float* __restrict__ MLpart,
                                                  bf16* __restrict__ Aout) {
  int idx = blockIdx.x * 2 + (threadIdx.x >> 7);
  if (idx >= NH * SEQ) return;
  int d = threadIdx.x & 127;
  int h = idx / SEQ, q = idx % SEQ;
  float m[NSPLIT];
  float M = -1e38f;
#pragma unroll
  for (int s = 0; s < NSPLIT; ++s) {
    m[s] = MLpart[(((size_t)s * NH + h) * SEQ + q) * 2];
    M = fmaxf(M, m[s]);
  }
  float L = 0.f, o = 0.f;
#pragma unroll
  for (int s = 0; s < NSPLIT; ++s) {
    float wgt = exp2f(m[s] - M);
    L += MLpart[(((size_t)s * NH + h) * SEQ + q) * 2 + 1] * wgt;
    o += Opart[((((size_t)s * NH + h) * SEQ + q)) * HD + d] * wgt;
  }
  Aout[(size_t)q * DIM + h * HD + d] = (bf16)(o / L);
}

// ---------------- host ----------------
extern "C" void kernel_launch(void* const* d_in, const int* in_sizes, int n_in,
                              void* d_out, int out_size, void* d_ws, size_t ws_size,
                              hipStream_t stream) {
  const float* x = (const float*)d_in[0];
  const float* Wq = (const float*)d_in[1];
  const float* bq = (const float*)d_in[2];
  const float* Wk = (const float*)d_in[3];
  const float* bk = (const float*)d_in[4];
  const float* Wv = (const float*)d_in[5];
  const float* bv = (const float*)d_in[6];
  const float* Wo = (const float*)d_in[7];
  const float* bo = (const float*)d_in[8];
  const float* nqw = (const float*)d_in[9];
  const float* nkw = (const float*)d_in[10];
  const float* cache_k = (const float*)d_in[11];
  const float* cache_v = (const float*)d_in[12];
  const float* fcos = (const float*)d_in[13];
  const float* fsin = (const float*)d_in[14];
  float* out = (float*)d_out;

  char* ws = (char*)d_ws;
  size_t off = 0;
  auto alloc = [&](size_t bytes) {
    char* p = ws + off;
    off += (bytes + 255) & ~(size_t)255;
    return p;
  };
  const int XN = SEQ * DIM;       // 2,396,160
  const int WN = DIM * DIM;       // 2,359,296
  bf16* xb = (bf16*)alloc((size_t)XN * 2);
  bf16* Wqb = (bf16*)alloc((size_t)WN * 2);
  bf16* Wkb = (bf16*)alloc((size_t)WN * 2);
  bf16* Wvb = (bf16*)alloc((size_t)WN * 2);
  bf16* Wob = (bf16*)alloc((size_t)WN * 2);
  bf16* QhB = (bf16*)alloc((size_t)NH * SEQ * HD * 2);
  bf16* Kcat = (bf16*)alloc((size_t)NH * KVP * HD * 2);
  bf16* Vt = (bf16*)alloc((size_t)NH * HD * KVP * 2);
  bf16* Aout = (bf16*)alloc((size_t)XN * 2);
  float* MLpart = (float*)alloc((size_t)NSPLIT * NH * SEQ * 2 * 4);
  // Opart (written by attn_split) overlays qraw/kraw/vraw (dead after build_vt);
  // NSPLIT*NH*SEQ*HD == 3*XN exactly.
  float* Opart = (float*)alloc((size_t)NSPLIT * NH * SEQ * HD * 4);
  float* qraw = Opart;
  float* kraw = qraw + XN;
  float* vraw = kraw + XN;

  CastBatch cb;
  cb.src[0] = x;  cb.dst[0] = xb;  cb.n[0] = XN;
  cb.src[1] = Wq; cb.dst[1] = Wqb; cb.n[1] = WN;
  cb.src[2] = Wk; cb.dst[2] = Wkb; cb.n[2] = WN;
  cb.src[3] = Wv; cb.dst[3] = Wvb; cb.n[3] = WN;
  cb.src[4] = Wo; cb.dst[4] = Wob; cb.n[4] = WN;
  castall<<<dim3((XN + 2047) / 2048, 5), 256, 0, stream>>>(cb);

  GemmBatch gqkv;
  gqkv.B[0] = Wqb; gqkv.B[1] = Wkb; gqkv.B[2] = Wvb;
  gqkv.bias[0] = bq; gqkv.bias[1] = bk; gqkv.bias[2] = bv;
  gqkv.C[0] = qraw; gqkv.C[1] = kraw; gqkv.C[2] = vraw;
  gemm_bt<<<dim3(13, 12, 3), 256, 0, stream>>>(xb, gqkv, SEQ);

  norm_rope<<<SEQ, 256, 0, stream>>>(qraw, kraw, nqw, nkw, fcos, fsin, QhB, Kcat);
  build_kcat<<<NEWBASE + (KVP - KV), 256, 0, stream>>>(cache_k, Kcat);
  build_vt<<<dim3(147, NH), 256, 0, stream>>>(cache_v, vraw, Vt);

  attn_split<<<dim3(NQT * NH * NSPLIT), 256, 0, stream>>>(QhB, Kcat, Vt, Opart, MLpart);
  attn_merge<<<(NH * SEQ + 1) / 2, 256, 0, stream>>>(Opart, MLpart, Aout);

  GemmBatch gout;
  gout.B[0] = Wob; gout.B[1] = Wob; gout.B[2] = Wob;
  gout.bias[0] = bo; gout.bias[1] = bo; gout.bias[2] = bo;
  gout.C[0] = out; gout.C[1] = out; gout.C[2] = out;
  gemm_bt<<<dim3(13, 12, 1), 256, 0, stream>>>(Aout, gout, SEQ);
}